// Round 1
// 128.735 us; speedup vs baseline: 1.0626x; 1.0626x over previous
//
#include <hip/hip_runtime.h>

#define SCALE_F 512.0f

// ws layout (float offsets)
#define WS_H     0        // B*S*E = 131072 floats
#define WS_GPART 131072   // 2048 blocks * 8 experts = 16384 floats

// ---------------- Kernel A: h[b,s,e] for all 8 experts + per-block gate partials
// grid 2048 blocks x 256 thr; 8 tokens/block (32KB LDS); wave w owns weight rows 4w..4w+3
// rows 0..7 = lora_A experts, rows 8..15 = gate_w experts. NO atomics.
// Gate waves (w>=2) accumulate per-lane partials across tokens and butterfly ONCE.
__global__ __launch_bounds__(256) void kA_h_gate(
    const float* __restrict__ x, const float* __restrict__ lora_A,
    const float* __restrict__ gate_w, float* __restrict__ h,
    float* __restrict__ gpart)
{
    const int tid  = threadIdx.x;
    const int w    = tid >> 6;
    const int lane = tid & 63;
    const int tok0 = blockIdx.x * 8;       // global token base

    __shared__ float xbuf[8 * 1024];       // 8 token rows, 32 KB

    // Wave's 4 weight rows in registers: 16 floats/lane/row at float4 idx lane+64j.
    float4 W[4][4];
#pragma unroll
    for (int rr = 0; rr < 4; ++rr) {
        const int row = 4 * w + rr;
        const float* rp = (row < 8) ? (lora_A + row * 1024)
                                    : (gate_w + (row - 8) * 1024);
        const float4* rp4 = (const float4*)rp;
#pragma unroll
        for (int j = 0; j < 4; ++j) W[rr][j] = rp4[lane + 64 * j];
    }

    // stage 8 token rows = 2048 float4, coalesced
    const float4* src = (const float4*)(x + (size_t)tok0 * 1024);
    float4* dst = (float4*)xbuf;
#pragma unroll
    for (int j = 0; j < 8; ++j) dst[tid + 256 * j] = src[tid + 256 * j];
    __syncthreads();

    float gacc[4] = {0.f, 0.f, 0.f, 0.f};

#pragma unroll 2
    for (int t = 0; t < 8; ++t) {
        const float4* xr = (const float4*)(xbuf + t * 1024);
        const float4 xv0 = xr[lane];
        const float4 xv1 = xr[lane + 64];
        const float4 xv2 = xr[lane + 128];
        const float4 xv3 = xr[lane + 192];

        float p[4];
#pragma unroll
        for (int rr = 0; rr < 4; ++rr) {
            const float4 a0 = W[rr][0], a1 = W[rr][1];
            const float4 a2 = W[rr][2], a3 = W[rr][3];
            float s;
            s  = xv0.x * a0.x + xv0.y * a0.y + xv0.z * a0.z + xv0.w * a0.w;
            s += xv1.x * a1.x + xv1.y * a1.y + xv1.z * a1.z + xv1.w * a1.w;
            s += xv2.x * a2.x + xv2.y * a2.y + xv2.z * a2.z + xv2.w * a2.w;
            s += xv3.x * a3.x + xv3.y * a3.y + xv3.z * a3.z + xv3.w * a3.w;
            p[rr] = s;
        }

        if (w < 2) {
            // per-token reduction needed for h rows
#pragma unroll
            for (int off = 32; off > 0; off >>= 1) {
                p[0] += __shfl_xor(p[0], off);
                p[1] += __shfl_xor(p[1], off);
                p[2] += __shfl_xor(p[2], off);
                p[3] += __shfl_xor(p[3], off);
            }
            if (lane == 0) {
                float4 hv = make_float4(p[0], p[1], p[2], p[3]);
                *(float4*)(h + (size_t)(tok0 + t) * 8 + w * 4) = hv;
            }
        } else {
            // gate rows: only the token-sum matters -> accumulate raw partials
            gacc[0] += p[0]; gacc[1] += p[1]; gacc[2] += p[2]; gacc[3] += p[3];
        }
    }

    if (w >= 2) {
        // single butterfly for the token-summed gate partials
#pragma unroll
        for (int off = 32; off > 0; off >>= 1) {
            gacc[0] += __shfl_xor(gacc[0], off);
            gacc[1] += __shfl_xor(gacc[1], off);
            gacc[2] += __shfl_xor(gacc[2], off);
            gacc[3] += __shfl_xor(gacc[3], off);
        }
        if (lane == 0) {
            float4 gv = make_float4(gacc[0], gacc[1], gacc[2], gacc[3]);
            *(float4*)(gpart + (size_t)blockIdx.x * 8 + (w - 2) * 4) = gv;
        }
    }
}

static __device__ __forceinline__ float4 f4add(float4 a, float4 b) {
    return make_float4(a.x + b.x, a.y + b.y, a.z + b.z, a.w + b.w);
}

// ---------------- Kernel B: fused gate-finalize + combine
// grid 2048 blocks x 256 thr; 8 tokens/block.
// Each block redundantly reduces its batch's 16KB gpart slice (L2-resident),
// does softmax+top2 locally, then out[tok,o] = c0*h0*B[i0,o] + c1*h1*B[i1,o].
__global__ __launch_bounds__(256) void kB_gate_combine(
    const float* __restrict__ h, const float* __restrict__ gpart,
    const float* __restrict__ gate_b, const float* __restrict__ lora_B,
    float* __restrict__ out)
{
    const int tid  = threadIdx.x;
    const int blk  = blockIdx.x;
    const int b    = blk >> 9;            // 512 blocks per batch
    const int tok0 = blk * 8;

    __shared__ float4 s4[256];
    __shared__ float  s_h[64];
    __shared__ float  s_logit[8];
    __shared__ int    s_sel[2];
    __shared__ float  s_coef[2];

    // 1) per-thread partial over the batch-b gate slice: 1024 float4 (16 KB)
    //    float4 idx parity == expert group (0..3 vs 4..7); parity of tid is
    //    preserved through the whole tree (all strides even).
    const float4* gp4 = (const float4*)(gpart + (size_t)b * 4096);
    float4 acc = gp4[tid];
    acc = f4add(acc, gp4[tid + 256]);
    acc = f4add(acc, gp4[tid + 512]);
    acc = f4add(acc, gp4[tid + 768]);
    s4[tid] = acc;

    // stage this block's h rows: 64 consecutive floats, coalesced
    if (tid < 64) s_h[tid] = h[(size_t)tok0 * 8 + tid];
    __syncthreads();

    if (tid < 64) {
        float4 a = f4add(f4add(s4[tid], s4[tid + 64]),
                         f4add(s4[tid + 128], s4[tid + 192]));
        s4[tid] = a;
    }
    __syncthreads();
    if (tid < 16) {
        float4 a = f4add(f4add(s4[tid], s4[tid + 16]),
                         f4add(s4[tid + 32], s4[tid + 48]));
        s4[tid] = a;
    }
    __syncthreads();
    if (tid < 2) {
        float4 a = s4[tid];
#pragma unroll
        for (int q = 2; q < 16; q += 2) a = f4add(a, s4[tid + q]);
        const float inv = 1.0f / 4096.0f;
        s_logit[tid * 4 + 0] = a.x * inv + gate_b[tid * 4 + 0];
        s_logit[tid * 4 + 1] = a.y * inv + gate_b[tid * 4 + 1];
        s_logit[tid * 4 + 2] = a.z * inv + gate_b[tid * 4 + 2];
        s_logit[tid * 4 + 3] = a.w * inv + gate_b[tid * 4 + 3];
    }
    __syncthreads();

    if (tid == 0) {
        float sc[8];
        float m = -1e30f;
#pragma unroll
        for (int q = 0; q < 8; ++q) { sc[q] = s_logit[q]; m = fmaxf(m, sc[q]); }
        float sum = 0.f;
#pragma unroll
        for (int q = 0; q < 8; ++q) { sc[q] = __expf(sc[q] - m); sum += sc[q]; }
        const float invs = 1.0f / sum;

        int i0 = 0;
#pragma unroll
        for (int q = 1; q < 8; ++q) if (sc[q] > sc[i0]) i0 = q;
        int i1 = (i0 == 0) ? 1 : 0;
#pragma unroll
        for (int q = 0; q < 8; ++q) if (q != i0 && sc[q] > sc[i1]) i1 = q;

        s_sel[0]  = i0;
        s_sel[1]  = i1;
        s_coef[0] = SCALE_F * sc[i0] * invs;
        s_coef[1] = SCALE_F * sc[i1] * invs;
    }
    __syncthreads();

    const int   i0 = s_sel[0];
    const int   i1 = s_sel[1];
    const float c0 = s_coef[0];
    const float c1 = s_coef[1];

    const float4 b0 = ((const float4*)(lora_B + i0 * 1024))[tid];
    const float4 b1 = ((const float4*)(lora_B + i1 * 1024))[tid];
    const float4 v0 = make_float4(c0 * b0.x, c0 * b0.y, c0 * b0.z, c0 * b0.w);
    const float4 v1 = make_float4(c1 * b1.x, c1 * b1.y, c1 * b1.z, c1 * b1.w);

    float4* out4 = (float4*)out;
#pragma unroll
    for (int t = 0; t < 8; ++t) {
        const float h0 = s_h[t * 8 + i0];
        const float h1 = s_h[t * 8 + i1];
        float4 r;
        r.x = h0 * v0.x + h1 * v1.x;
        r.y = h0 * v0.y + h1 * v1.y;
        r.z = h0 * v0.z + h1 * v1.z;
        r.w = h0 * v0.w + h1 * v1.w;
        out4[(size_t)(tok0 + t) * 256 + tid] = r;
    }
}

extern "C" void kernel_launch(void* const* d_in, const int* in_sizes, int n_in,
                              void* d_out, int out_size, void* d_ws, size_t ws_size,
                              hipStream_t stream) {
    const float* x      = (const float*)d_in[0];
    const float* lora_A = (const float*)d_in[1];
    const float* lora_B = (const float*)d_in[2];
    const float* gate_w = (const float*)d_in[3];
    const float* gate_b = (const float*)d_in[4];
    float* out = (float*)d_out;

    float* ws    = (float*)d_ws;
    float* h     = ws + WS_H;
    float* gpart = ws + WS_GPART;

    kA_h_gate<<<2048, 256, 0, stream>>>(x, lora_A, gate_w, h, gpart);
    kB_gate_combine<<<2048, 256, 0, stream>>>(h, gpart, gate_b, lora_B, out);
}